// Round 5
// baseline (320.859 us; speedup 1.0000x reference)
//
#include <hip/hip_runtime.h>

// SoftDTW: B=64, N=512, M=512, DIM=64, GAMMA=1.0, BANDWIDTH=0, BIG=1e10
constexpr int Bc   = 64;
constexpr int Nc   = 512;
constexpr int Mc   = 512;
constexpr int DIMc = 64;
constexpr float BIGc = 1e10f;
constexpr int CELLS = Nc * Mc;          // 1 MiB/batch row-major D (prescaled by log2e)
constexpr float LOG2E = 1.442695041f;
constexpr float LN2   = 0.6931471806f;

struct TrueC  { static constexpr bool value = true;  };
struct FalseC { static constexpr bool value = false; };

// lane l <- lane l-1 across the 64-lane wave; lane 0 <- old
__device__ __forceinline__ float dpp_shr1_f(float v, float old) {
    return __builtin_bit_cast(float, __builtin_amdgcn_update_dpp(
        __builtin_bit_cast(int, old), __builtin_bit_cast(int, v), 0x138, 0xF, 0xF, false));
}
__device__ __forceinline__ float f4c(const float4 v, int c) {
    switch (c & 3) { case 0: return v.x; case 1: return v.y;
                     case 2: return v.z; default: return v.w; }
}

// ---------------- Kernel A: D[b][n][m] = ||X[b,n]-Y[b,m]||^2 * log2e, row-major ---
__global__ __launch_bounds__(256)
void compute_D(const float* __restrict__ X, const float* __restrict__ Y,
               float* __restrict__ Dc)
{
    const int b   = blockIdx.x;
    const int nt  = blockIdx.y;
    const int tid = threadIdx.x;
    const int ty  = tid >> 4, tx = tid & 15;

    __shared__ float Xs[DIMc][68];       // [dim][row], padded
    __shared__ float Ys[DIMc][68];

    const float* Xb = X + ((size_t)b * Nc + (size_t)nt * 64) * DIMc;
    const float* Yb = Y + (size_t)b * Mc * DIMc;
    float*       Db = Dc + (size_t)b * CELLS;
    const int n0 = nt * 64;

    {
        const float4* Xb4 = reinterpret_cast<const float4*>(Xb);
        for (int c4 = tid; c4 < 64 * DIMc / 4; c4 += 256) {
            float4 v = Xb4[c4];
            const int n = c4 >> 4, k0 = (c4 & 15) * 4;
            Xs[k0+0][n] = v.x; Xs[k0+1][n] = v.y; Xs[k0+2][n] = v.z; Xs[k0+3][n] = v.w;
        }
    }

    for (int mt = 0; mt < Mc / 64; ++mt) {
        __syncthreads();
        {
            const float4* Yb4 = reinterpret_cast<const float4*>(Yb + (size_t)mt * 64 * DIMc);
            for (int c4 = tid; c4 < 64 * DIMc / 4; c4 += 256) {
                float4 v = Yb4[c4];
                const int n = c4 >> 4, k0 = (c4 & 15) * 4;
                Ys[k0+0][n] = v.x; Ys[k0+1][n] = v.y; Ys[k0+2][n] = v.z; Ys[k0+3][n] = v.w;
            }
        }
        __syncthreads();

        float acc[4][4];
        #pragma unroll
        for (int r = 0; r < 4; ++r)
            #pragma unroll
            for (int cc = 0; cc < 4; ++cc) acc[r][cc] = 0.f;

        #pragma unroll 8
        for (int k = 0; k < DIMc; ++k) {
            float4 xv = *reinterpret_cast<const float4*>(&Xs[k][ty * 4]);
            float4 yv = *reinterpret_cast<const float4*>(&Ys[k][tx * 4]);
            float xr[4] = {xv.x, xv.y, xv.z, xv.w};
            float yr[4] = {yv.x, yv.y, yv.z, yv.w};
            #pragma unroll
            for (int r = 0; r < 4; ++r)
                #pragma unroll
                for (int cc = 0; cc < 4; ++cc) {
                    float d = xr[r] - yr[cc];
                    acc[r][cc] = fmaf(d, d, acc[r][cc]);
                }
        }

        // coalesced row-major float4 stores, prescaled by log2e
        #pragma unroll
        for (int r = 0; r < 4; ++r) {
            const int n = n0 + ty * 4 + r;
            float4 st = make_float4(acc[r][0]*LOG2E, acc[r][1]*LOG2E,
                                    acc[r][2]*LOG2E, acc[r][3]*LOG2E);
            *reinterpret_cast<float4*>(&Db[(size_t)n * Mc + mt * 64 + tx * 4]) = st;
        }
    }
}

// ---------------- Kernel B: 2-blocks-per-batch wave-systolic recurrence ----------
// Global wave W = blk*4 + wl owns rows 64W+1..64W+64 (1-based). Values prescaled
// by log2e (v_exp_f32/v_log_f32 are base-2). Intra-wave neighbor: DPP wave_shr:1.
// Intra-block wave boundary: 2-parity LDS ring (adjacent windows -> no race).
// Inter-block boundary (row 256 -> 257): global bnd buffer + release/acquire
// progress flag; consumer lags 2 slots so polls succeed immediately.
__global__ __launch_bounds__(256)
void softdtw_sys2(const float* __restrict__ Dc, const int* __restrict__ lengths,
                  float* __restrict__ out, float* __restrict__ bndG,
                  int* __restrict__ prog)
{
    const int bid  = blockIdx.x;
    const int b    = bid >> 1;
    const int blk  = bid & 1;
    const int t    = threadIdx.x;
    const int lane = t & 63;
    const int wl   = __builtin_amdgcn_readfirstlane(t >> 6);   // scalar 0..3
    const int W    = blk * 4 + wl;
    const int L    = lengths[b];
    const int r    = (W << 6) + lane;       // 0-based row
    const int i    = r + 1;

    const float* Dbat = Dc + (size_t)b * CELLS;
    float* bndB = bndG + b * 1024;

    __shared__ float ring[4][64];
    if (t < 64) ring[0][t] = BIGc;          // row-0 boundary for W=0 lane0
    __syncthreads();

    const bool isCons = (blk == 1 && wl == 0);
    const bool isProd = (blk == 0 && wl == 3);
    const bool l0     = (lane == 0);
    const bool iok    = (i <= L);
    const int  r511   = r * 511;            // row-major: idx = r*511 + g (g = n+m)
    const int  gcap   = (i == L) ? (L + Mc - 2) : -1;

    float own = BIGc, nb1 = BIGc, nb2 = BIGc, res = 0.f;
    if (W == 0 && l0) nb2 = 0.f;            // R[0][0] = 0 seed

    const int qf = (W == 0) ? 0 : 2 * W - 1;           // warm-up window first
    const int ql = min((64 * W + 574) >> 5, 31);

    float Dbuf[32];
    #pragma unroll
    for (int s = 0; s < 32; ++s)
        Dbuf[s] = Dbat[min(qf * 32 + s, 1022) + r511];

    const int c0 = blk ? 12 : 0;
    const int c1 = blk ? 39 : 26;

    for (int c = c0; c <= c1; ++c) {
        const int q = c - W - blk;          // blk = extra 1-slot lag for block 1
        const bool doWork = (q >= qf) && (q <= ql);
        if (doWork) {
            const int g0 = q * 32;

            float4 rv[8];
            if (isCons) {
                if (g0 <= 767) {            // producer's last real window is 23
                    const int need = q + 1;
                    int it = 0;
                    while (__hip_atomic_load(prog + b, __ATOMIC_ACQUIRE,
                                             __HIP_MEMORY_SCOPE_AGENT) < need
                           && it < (1 << 24)) { ++it; __builtin_amdgcn_s_sleep(2); }
                    const float4* bp = reinterpret_cast<const float4*>(bndB + g0);
                    #pragma unroll
                    for (int u = 0; u < 8; ++u) rv[u] = bp[u];
                } else {
                    float4 bb = make_float4(BIGc, BIGc, BIGc, BIGc);
                    #pragma unroll
                    for (int u = 0; u < 8; ++u) rv[u] = bb;
                }
            } else {
                const float4* rp = reinterpret_cast<const float4*>(&ring[wl][g0 & 63]);
                #pragma unroll
                for (int u = 0; u < 8; ++u) rv[u] = rp[u];
            }

            const bool fast = (q >= 2 * W + 2) && (q <= 2 * W + 15) &&
                              ((W << 6) + 64 <= L);

            auto body = [&](auto FASTC) {
                constexpr bool FAST = decltype(FASTC)::value;
                #pragma unroll
                for (int s = 0; s < 32; ++s) {
                    const int g = g0 + s;
                    const float mn = fminf(nb2, fminf(nb1, own));
                    const float e  = __builtin_amdgcn_exp2f(mn - nb2)
                                   + __builtin_amdgcn_exp2f(mn - nb1)
                                   + __builtin_amdgcn_exp2f(mn - own);
                    const float sm = mn - __builtin_amdgcn_logf(e);   // log2
                    float v = Dbuf[s] + sm;
                    if (!FAST) {
                        const bool jok = (unsigned)(g - r) < (unsigned)Mc;
                        v = (jok && iok) ? v : BIGc;
                    }
                    res = (g == gcap) ? v : res;
                    Dbuf[s] = Dbat[min(g0 + 32 + s, 1022) + r511];    // next window
                    if (isProd)      { if (lane == 63) bndB[g] = v; }
                    else if (wl < 3) { if (lane == 63) ring[wl + 1][(g0 & 63) + s] = v; }
                    const float sh = dpp_shr1_f(v, BIGc);
                    nb2 = nb1;
                    nb1 = l0 ? f4c(rv[s >> 2], s) : sh;
                    own = v;
                }
            };
            if (fast) body(TrueC{}); else body(FalseC{});

            if (isProd && lane == 63)
                __hip_atomic_store(prog + b, q + 1, __ATOMIC_RELEASE,
                                   __HIP_MEMORY_SCOPE_AGENT);
        }
        asm volatile("s_waitcnt lgkmcnt(0)" ::: "memory");
        __builtin_amdgcn_s_barrier();
        asm volatile("" ::: "memory");
    }

    if (i == L) out[b] = res * LN2;
}

// ---------------- Fallback (no workspace): fused on-the-fly D --------------------
__global__ __launch_bounds__(512)
void softdtw_fused(const float* __restrict__ X, const float* __restrict__ Y,
                   const int* __restrict__ lengths, float* __restrict__ out)
{
    const int b = blockIdx.x;
    const int t = threadIdx.x;
    const int i = t + 1;
    const int L = lengths[b];

    __shared__ float diag[3][Nc + 1];
    for (int c = t; c <= Nc; c += 512) {
        diag[0][c] = (c == 0) ? 0.f : BIGc;
        diag[1][c] = BIGc;
    }
    float xr[DIMc];
    const float* Xrow = X + ((size_t)b * Nc + t) * DIMc;
    #pragma unroll
    for (int d = 0; d < DIMc; d += 4) {
        float4 v = *reinterpret_cast<const float4*>(Xrow + d);
        xr[d] = v.x; xr[d+1] = v.y; xr[d+2] = v.z; xr[d+3] = v.w;
    }
    const float* Yb = Y + (size_t)b * Mc * DIMc;
    __syncthreads();

    float result = BIGc;
    int cur = 2, p1 = 1, p2 = 0;
    for (int k = 2; k <= Nc + Mc; ++k) {
        const int j = k - i;
        const bool valid = (j >= 1) && (j <= Mc) && (i <= L);
        float Dval = 0.f;
        if (valid) {
            const float* Yrow = Yb + (size_t)(j - 1) * DIMc;
            float s = 0.f;
            #pragma unroll
            for (int d = 0; d < DIMc; d += 4) {
                float4 v = *reinterpret_cast<const float4*>(Yrow + d);
                float d0 = xr[d] - v.x, d1 = xr[d+1] - v.y;
                float d2 = xr[d+2] - v.z, d3 = xr[d+3] - v.w;
                s = fmaf(d0,d0,s); s = fmaf(d1,d1,s); s = fmaf(d2,d2,s); s = fmaf(d3,d3,s);
            }
            Dval = s;
        }
        const float a2 = diag[p2][i-1], a1 = diag[p1][i-1], a0 = diag[p1][i];
        const float mn = fminf(a2, fminf(a1, a0));
        const float sm = mn - __logf(__expf(mn-a2) + __expf(mn-a1) + __expf(mn-a0));
        const float val = valid ? (Dval + sm) : BIGc;
        diag[cur][i] = val;
        if (t == 0) diag[cur][0] = BIGc;
        if (k == L + Mc && i == L) result = val;
        __syncthreads();
        const int tmp = p2; p2 = p1; p1 = cur; cur = tmp;
    }
    if (i == L) out[b] = result;
}

extern "C" void kernel_launch(void* const* d_in, const int* in_sizes, int n_in,
                              void* d_out, int out_size, void* d_ws, size_t ws_size,
                              hipStream_t stream) {
    const float* X = (const float*)d_in[0];
    const float* Y = (const float*)d_in[1];
    const int* lengths = (const int*)d_in[2];
    float* out = (float*)d_out;

    const size_t dcBytes  = (size_t)Bc * CELLS * sizeof(float);   // 64 MiB
    const size_t bndBytes = (size_t)Bc * 1024 * sizeof(float);    // 256 KiB
    const size_t need = dcBytes + bndBytes + Bc * sizeof(int);

    if (ws_size >= need) {
        char* base = (char*)d_ws;
        float* Dc   = (float*)base;
        float* bndG = (float*)(base + dcBytes);
        int*   prog = (int*)(base + dcBytes + bndBytes);

        hipMemsetAsync(prog, 0, Bc * sizeof(int), stream);
        compute_D<<<dim3(Bc, Nc / 64), 256, 0, stream>>>(X, Y, Dc);
        softdtw_sys2<<<Bc * 2, 256, 0, stream>>>(Dc, lengths, out, bndG, prog);
    } else {
        softdtw_fused<<<Bc, 512, 0, stream>>>(X, Y, lengths, out);
    }
}

// Round 6
// 308.268 us; speedup vs baseline: 1.0408x; 1.0408x over previous
//
#include <hip/hip_runtime.h>

// SoftDTW: B=64, N=512, M=512, DIM=64, GAMMA=1.0, BANDWIDTH=0, BIG=1e10
constexpr int Bc   = 64;
constexpr int Nc   = 512;
constexpr int Mc   = 512;
constexpr int DIMc = 64;
constexpr float BIGc = 1e10f;
constexpr int CELLS = Nc * Mc;          // 1 MiB/batch row-major D (prescaled by log2e)
constexpr float LOG2E = 1.442695041f;
constexpr float LN2   = 0.6931471806f;

struct TrueC  { static constexpr bool value = true;  };
struct FalseC { static constexpr bool value = false; };

// lane l <- lane l-1 across the 64-lane wave; lane 0 <- old
__device__ __forceinline__ float dpp_shr1_f(float v, float old) {
    return __builtin_bit_cast(float, __builtin_amdgcn_update_dpp(
        __builtin_bit_cast(int, old), __builtin_bit_cast(int, v), 0x138, 0xF, 0xF, false));
}
__device__ __forceinline__ float f4c(const float4 v, int c) {
    switch (c & 3) { case 0: return v.x; case 1: return v.y;
                     case 2: return v.z; default: return v.w; }
}

// ---------------- Kernel A: D[b][n][m] = ||X[b,n]-Y[b,m]||^2 * log2e, row-major ---
__global__ __launch_bounds__(256)
void compute_D(const float* __restrict__ X, const float* __restrict__ Y,
               float* __restrict__ Dc)
{
    const int b   = blockIdx.x;
    const int nt  = blockIdx.y;
    const int tid = threadIdx.x;
    const int ty  = tid >> 4, tx = tid & 15;

    __shared__ float Xs[DIMc][68];       // [dim][row], padded
    __shared__ float Ys[DIMc][68];

    const float* Xb = X + ((size_t)b * Nc + (size_t)nt * 64) * DIMc;
    const float* Yb = Y + (size_t)b * Mc * DIMc;
    float*       Db = Dc + (size_t)b * CELLS;
    const int n0 = nt * 64;

    {
        const float4* Xb4 = reinterpret_cast<const float4*>(Xb);
        for (int c4 = tid; c4 < 64 * DIMc / 4; c4 += 256) {
            float4 v = Xb4[c4];
            const int n = c4 >> 4, k0 = (c4 & 15) * 4;
            Xs[k0+0][n] = v.x; Xs[k0+1][n] = v.y; Xs[k0+2][n] = v.z; Xs[k0+3][n] = v.w;
        }
    }

    for (int mt = 0; mt < Mc / 64; ++mt) {
        __syncthreads();
        {
            const float4* Yb4 = reinterpret_cast<const float4*>(Yb + (size_t)mt * 64 * DIMc);
            for (int c4 = tid; c4 < 64 * DIMc / 4; c4 += 256) {
                float4 v = Yb4[c4];
                const int n = c4 >> 4, k0 = (c4 & 15) * 4;
                Ys[k0+0][n] = v.x; Ys[k0+1][n] = v.y; Ys[k0+2][n] = v.z; Ys[k0+3][n] = v.w;
            }
        }
        __syncthreads();

        float acc[4][4];
        #pragma unroll
        for (int r = 0; r < 4; ++r)
            #pragma unroll
            for (int cc = 0; cc < 4; ++cc) acc[r][cc] = 0.f;

        #pragma unroll 8
        for (int k = 0; k < DIMc; ++k) {
            float4 xv = *reinterpret_cast<const float4*>(&Xs[k][ty * 4]);
            float4 yv = *reinterpret_cast<const float4*>(&Ys[k][tx * 4]);
            float xr[4] = {xv.x, xv.y, xv.z, xv.w};
            float yr[4] = {yv.x, yv.y, yv.z, yv.w};
            #pragma unroll
            for (int r = 0; r < 4; ++r)
                #pragma unroll
                for (int cc = 0; cc < 4; ++cc) {
                    float d = xr[r] - yr[cc];
                    acc[r][cc] = fmaf(d, d, acc[r][cc]);
                }
        }

        #pragma unroll
        for (int r = 0; r < 4; ++r) {
            const int n = n0 + ty * 4 + r;
            float4 st = make_float4(acc[r][0]*LOG2E, acc[r][1]*LOG2E,
                                    acc[r][2]*LOG2E, acc[r][3]*LOG2E);
            *reinterpret_cast<float4*>(&Db[(size_t)n * Mc + mt * 64 + tx * 4]) = st;
        }
    }
}

// ---------------- Kernel B: 8-wave single-block systolic recurrence --------------
// Wave W owns rows r = 64W..64W+63 (0-based). Neighbor row value via DPP
// wave_shr:1; wave boundary via 2-parity LDS ring (windows alternate base 0/32,
// writer is one c-step ahead of reader, overwrite is one c-step after the read).
// Values prescaled by log2e (v_exp/v_log are base-2). One raw s_barrier per
// 32-step window (lgkm drain only; D prefetch loads stay in flight).
// Interior windows run a mask-free 17-instruction body with immediate-offset
// D refill; boundary windows carry masks, clamped refill, and result capture.
__global__ __launch_bounds__(512)
void softdtw_sys8(const float* __restrict__ Dc, const int* __restrict__ lengths,
                  float* __restrict__ out)
{
    const int b    = blockIdx.x;
    const int t    = threadIdx.x;
    const int lane = t & 63;
    const int W    = __builtin_amdgcn_readfirstlane(t >> 6);   // scalar 0..7
    const int L    = lengths[b];
    const int r    = (W << 6) + lane;       // 0-based row
    const int i    = r + 1;
    const float* Dbat = Dc + (size_t)b * CELLS;

    __shared__ float ring[9][64];           // ring[W]: row 64W-1 values; [8] = sink
    if (t < 64) ring[0][t] = BIGc;
    __syncthreads();

    const bool l0   = (lane == 0);
    const bool iok  = (i <= L);
    const int  r511 = r * 511;              // row-major: idx = r*512 + (g-r) = r511 + g
    const int  rend = r + 511;              // last valid g for this row
    const int  gcap = (i == L) ? (L + 510) : -1;   // diag of cell (L, 512)

    float own = BIGc, nb1 = BIGc, nb2 = BIGc, res = 0.f;
    if (W == 0 && l0) nb2 = 0.f;            // R[0][0] = 0 seed

    const int qf = (W == 0) ? 0 : (2 * W - 1);     // warm-up window first
    const int ql = 2 * W + 17;                     // last needed window (<= 31)

    // prefill D for window qf (clamped; out-of-range cells masked at use)
    float Dbuf[32];
    #pragma unroll
    for (int s = 0; s < 32; ++s)
        Dbuf[s] = Dbat[r511 + min(qf * 32 + s, rend)];

    for (int c = 0; c < 39; ++c) {
        const int q = c - W;
        if (q >= qf && q <= ql) {
            const int g0 = q * 32;

            // batched ring window read (uniform addr broadcast, off the chain)
            float4 rv[8];
            {
                const float4* rp = reinterpret_cast<const float4*>(&ring[W][g0 & 63]);
                #pragma unroll
                for (int u = 0; u < 8; ++u) rv[u] = rp[u];
            }
            float* ringN = &ring[W + 1][g0 & 63];
            const float* pF = Dbat + (r511 + g0 + 32);    // refill base (fast path)

            const bool fast = (q >= 2 * W + 2) && (q <= 2 * W + 15) &&
                              ((W << 6) + 64 <= L);

            auto body = [&](auto FASTC) {
                constexpr bool FAST = decltype(FASTC)::value;
                #pragma unroll
                for (int s = 0; s < 32; ++s) {
                    const int g = g0 + s;
                    const float mn = fminf(nb2, fminf(nb1, own));
                    const float e  = __builtin_amdgcn_exp2f(mn - nb2)
                                   + __builtin_amdgcn_exp2f(mn - nb1)
                                   + __builtin_amdgcn_exp2f(mn - own);
                    const float sm = mn - __builtin_amdgcn_logf(e);   // log2
                    float v = Dbuf[s] + sm;
                    if (FAST) {
                        Dbuf[s] = pF[s];                  // immediate-offset refill
                    } else {
                        const bool jok = (unsigned)(g - r) < (unsigned)Mc;
                        v = (jok && iok) ? v : BIGc;
                        res = (g == gcap) ? v : res;      // capture only in slow windows
                        Dbuf[s] = Dbat[r511 + min(g + 32, rend)];
                    }
                    if (lane == 63) ringN[s] = v;         // boundary export
                    const float sh = dpp_shr1_f(v, BIGc);
                    nb2 = nb1;
                    nb1 = l0 ? f4c(rv[s >> 2], s) : sh;
                    own = v;
                }
            };
            if (fast) body(TrueC{}); else body(FalseC{});
        }
        asm volatile("s_waitcnt lgkmcnt(0)" ::: "memory");  // ring writes visible
        __builtin_amdgcn_s_barrier();                       // no vmcnt drain
        asm volatile("" ::: "memory");
    }

    if (i == L) out[b] = res * LN2;
}

// ---------------- Fallback (no workspace): fused on-the-fly D --------------------
__global__ __launch_bounds__(512)
void softdtw_fused(const float* __restrict__ X, const float* __restrict__ Y,
                   const int* __restrict__ lengths, float* __restrict__ out)
{
    const int b = blockIdx.x;
    const int t = threadIdx.x;
    const int i = t + 1;
    const int L = lengths[b];

    __shared__ float diag[3][Nc + 1];
    for (int c = t; c <= Nc; c += 512) {
        diag[0][c] = (c == 0) ? 0.f : BIGc;
        diag[1][c] = BIGc;
    }
    float xr[DIMc];
    const float* Xrow = X + ((size_t)b * Nc + t) * DIMc;
    #pragma unroll
    for (int d = 0; d < DIMc; d += 4) {
        float4 v = *reinterpret_cast<const float4*>(Xrow + d);
        xr[d] = v.x; xr[d+1] = v.y; xr[d+2] = v.z; xr[d+3] = v.w;
    }
    const float* Yb = Y + (size_t)b * Mc * DIMc;
    __syncthreads();

    float result = BIGc;
    int cur = 2, p1 = 1, p2 = 0;
    for (int k = 2; k <= Nc + Mc; ++k) {
        const int j = k - i;
        const bool valid = (j >= 1) && (j <= Mc) && (i <= L);
        float Dval = 0.f;
        if (valid) {
            const float* Yrow = Yb + (size_t)(j - 1) * DIMc;
            float s = 0.f;
            #pragma unroll
            for (int d = 0; d < DIMc; d += 4) {
                float4 v = *reinterpret_cast<const float4*>(Yrow + d);
                float d0 = xr[d] - v.x, d1 = xr[d+1] - v.y;
                float d2 = xr[d+2] - v.z, d3 = xr[d+3] - v.w;
                s = fmaf(d0,d0,s); s = fmaf(d1,d1,s); s = fmaf(d2,d2,s); s = fmaf(d3,d3,s);
            }
            Dval = s;
        }
        const float a2 = diag[p2][i-1], a1 = diag[p1][i-1], a0 = diag[p1][i];
        const float mn = fminf(a2, fminf(a1, a0));
        const float sm = mn - __logf(__expf(mn-a2) + __expf(mn-a1) + __expf(mn-a0));
        const float val = valid ? (Dval + sm) : BIGc;
        diag[cur][i] = val;
        if (t == 0) diag[cur][0] = BIGc;
        if (k == L + Mc && i == L) result = val;
        __syncthreads();
        const int tmp = p2; p2 = p1; p1 = cur; cur = tmp;
    }
    if (i == L) out[b] = result;
}

extern "C" void kernel_launch(void* const* d_in, const int* in_sizes, int n_in,
                              void* d_out, int out_size, void* d_ws, size_t ws_size,
                              hipStream_t stream) {
    const float* X = (const float*)d_in[0];
    const float* Y = (const float*)d_in[1];
    const int* lengths = (const int*)d_in[2];
    float* out = (float*)d_out;

    const size_t need = (size_t)Bc * CELLS * sizeof(float);   // 64 MiB
    if (ws_size >= need) {
        float* Dc = (float*)d_ws;
        compute_D<<<dim3(Bc, Nc / 64), 256, 0, stream>>>(X, Y, Dc);
        softdtw_sys8<<<Bc, 512, 0, stream>>>(Dc, lengths, out);
    } else {
        softdtw_fused<<<Bc, 512, 0, stream>>>(X, Y, lengths, out);
    }
}

// Round 7
// 199.943 us; speedup vs baseline: 1.6047x; 1.5418x over previous
//
#include <hip/hip_runtime.h>

// SoftDTW: B=64, N=512, M=512, DIM=64, GAMMA=1.0, BANDWIDTH=0, BIG=1e10
constexpr int Bc   = 64;
constexpr int Nc   = 512;
constexpr int Mc   = 512;
constexpr int DIMc = 64;
constexpr float BIGc = 1e10f;
constexpr int CELLS = Nc * Mc;          // 1 MiB/batch row-major D (prescaled by log2e)
constexpr float LOG2E = 1.442695041f;
constexpr float LN2   = 0.6931471806f;

// kernel-B LDS geometry (dynamic, 128 KiB total = guide-verified size)
constexpr int STRIDE   = 63;                   // words per step-slot (bank-free)
constexpr int SBUF     = 32 * STRIDE;          // 2016 words per stage buffer
constexpr int WAVE_LDS = 2 * SBUF;             // double-buffered per wave
constexpr int RING_OFF = 8 * WAVE_LDS;         // 32256 words
constexpr int LDS_WORDS = RING_OFF + 8 * 64;   // 32768 words = 131072 B

struct TrueC  { static constexpr bool value = true;  };
struct FalseC { static constexpr bool value = false; };

// lane l <- lane l-1 across the 64-lane wave; lane 0 <- old
__device__ __forceinline__ float dpp_shr1_f(float v, float old) {
    return __builtin_bit_cast(float, __builtin_amdgcn_update_dpp(
        __builtin_bit_cast(int, old), __builtin_bit_cast(int, v), 0x138, 0xF, 0xF, false));
}
__device__ __forceinline__ float f4c(const float4 v, int c) {
    switch (c & 3) { case 0: return v.x; case 1: return v.y;
                     case 2: return v.z; default: return v.w; }
}
__device__ __forceinline__ void f4set(float4& d, int c, float v) {
    switch (c & 3) { case 0: d.x = v; break; case 1: d.y = v; break;
                     case 2: d.z = v; break; default: d.w = v; }
}

// ---------------- Kernel A: D[b][n][m] = ||X[b,n]-Y[b,m]||^2 * log2e, row-major ---
__global__ __launch_bounds__(256)
void compute_D(const float* __restrict__ X, const float* __restrict__ Y,
               float* __restrict__ Dc)
{
    const int b   = blockIdx.x;
    const int nt  = blockIdx.y;
    const int tid = threadIdx.x;
    const int ty  = tid >> 4, tx = tid & 15;

    __shared__ float Xs[DIMc][68];       // [dim][row], padded
    __shared__ float Ys[DIMc][68];

    const float* Xb = X + ((size_t)b * Nc + (size_t)nt * 64) * DIMc;
    const float* Yb = Y + (size_t)b * Mc * DIMc;
    float*       Db = Dc + (size_t)b * CELLS;
    const int n0 = nt * 64;

    {
        const float4* Xb4 = reinterpret_cast<const float4*>(Xb);
        for (int c4 = tid; c4 < 64 * DIMc / 4; c4 += 256) {
            float4 v = Xb4[c4];
            const int n = c4 >> 4, k0 = (c4 & 15) * 4;
            Xs[k0+0][n] = v.x; Xs[k0+1][n] = v.y; Xs[k0+2][n] = v.z; Xs[k0+3][n] = v.w;
        }
    }

    for (int mt = 0; mt < Mc / 64; ++mt) {
        __syncthreads();
        {
            const float4* Yb4 = reinterpret_cast<const float4*>(Yb + (size_t)mt * 64 * DIMc);
            for (int c4 = tid; c4 < 64 * DIMc / 4; c4 += 256) {
                float4 v = Yb4[c4];
                const int n = c4 >> 4, k0 = (c4 & 15) * 4;
                Ys[k0+0][n] = v.x; Ys[k0+1][n] = v.y; Ys[k0+2][n] = v.z; Ys[k0+3][n] = v.w;
            }
        }
        __syncthreads();

        float acc[4][4];
        #pragma unroll
        for (int r = 0; r < 4; ++r)
            #pragma unroll
            for (int cc = 0; cc < 4; ++cc) acc[r][cc] = 0.f;

        #pragma unroll 8
        for (int k = 0; k < DIMc; ++k) {
            float4 xv = *reinterpret_cast<const float4*>(&Xs[k][ty * 4]);
            float4 yv = *reinterpret_cast<const float4*>(&Ys[k][tx * 4]);
            float xr[4] = {xv.x, xv.y, xv.z, xv.w};
            float yr[4] = {yv.x, yv.y, yv.z, yv.w};
            #pragma unroll
            for (int r = 0; r < 4; ++r)
                #pragma unroll
                for (int cc = 0; cc < 4; ++cc) {
                    float d = xr[r] - yr[cc];
                    acc[r][cc] = fmaf(d, d, acc[r][cc]);
                }
        }

        #pragma unroll
        for (int r = 0; r < 4; ++r) {
            const int n = n0 + ty * 4 + r;
            float4 st = make_float4(acc[r][0]*LOG2E, acc[r][1]*LOG2E,
                                    acc[r][2]*LOG2E, acc[r][3]*LOG2E);
            *reinterpret_cast<float4*>(&Db[(size_t)n * Mc + mt * 64 + tx * 4]) = st;
        }
    }
}

// ---------------- Kernel B: 8-wave systolic with LDS-staged D --------------------
// Wave W owns rows r = 64W..64W+63. Fast (interior) windows read D from a
// per-wave LDS stage buffer (coalesced global->reg->LDS transpose, T14 split:
// loads issued before the 32-step body, LDS writes after). Boundary windows use
// a clamped per-lane register prefetch (Dslow), fetched one window ahead.
// Neighbor row value via DPP wave_shr:1; wave boundary via 2-parity ring slots
// written as 8x b128 at window end from packed regs. One raw s_barrier per
// window (lgkm drain only; global loads stay in flight).
__global__ __launch_bounds__(512)
void softdtw_sys8(const float* __restrict__ Dc, const int* __restrict__ lengths,
                  float* __restrict__ out)
{
    extern __shared__ float lds[];
    const int b    = blockIdx.x;
    const int t    = threadIdx.x;
    const int lane = t & 63;
    const int W    = __builtin_amdgcn_readfirstlane(t >> 6);   // scalar 0..7
    const int L    = lengths[b];
    const int r    = (W << 6) + lane;       // 0-based row
    const int i    = r + 1;
    const float* Dbat = Dc + (size_t)b * CELLS;

    float* stageW = lds + W * WAVE_LDS;

    if (t < 64) lds[RING_OFF + t] = BIGc;   // ring[0] (no writer)
    __syncthreads();

    const bool l0   = (lane == 0);
    const bool iok  = (i <= L);
    const int  r511 = r * 511;              // row-major: idx = r*512 + (g-r) = r511 + g
    const int  rend = r + 511;              // last valid g for this row
    const int  gcap = (i == L) ? (L + 510) : -1;   // diag of cell (L, 512)
    const int  qcap = (L + 510) >> 5;
    const bool rowsOK = ((W << 6) + 64) <= L;
    const int  qf = (W == 0) ? 0 : (2 * W - 1);    // warm-up window first
    const int  ql = 2 * W + 17;

    float own = BIGc, nb1 = BIGc, nb2 = BIGc, res = 0.f;
    if (W == 0 && l0) nb2 = 0.f;            // R[0][0] seed

    // per-lane constant address pieces
    const int lbase = (((W << 6) + (lane >> 3)) * 511) + ((lane & 7) << 2); // stage loads
    const int wbw   = ((lane & 7) << 2) * STRIDE + (lane >> 3);             // stage writes

    float Dslow[32];
    auto prefSlow = [&](int qn) {
        const int gb = qn * 32;
        #pragma unroll
        for (int s = 0; s < 32; ++s)
            Dslow[s] = Dbat[r511 + min(max(gb + s, r), rend)];
    };
    prefSlow(qf);                           // first window is always a slow one

    for (int c = 0; c < 39; ++c) {
        const int q = c - W;
        if (q >= qf && q <= ql) {
            const int g0 = q * 32;

            // ring window in (uniform broadcast b128 reads, off the chain)
            float4 rv[8];
            {
                const float4* rp = reinterpret_cast<const float4*>(
                    lds + RING_OFF + W * 64 + (g0 & 63));
                #pragma unroll
                for (int u = 0; u < 8; ++u) rv[u] = rp[u];
            }

            const bool fastC = rowsOK && q >= 2*W+2 && q <= 2*W+15 && q != qcap;
            const bool nxtF  = rowsOK && (q+1) >= 2*W+2 && (q+1) <= 2*W+15 && (q+1) != qcap;

            // issue next-window stage loads EARLY (coalesced; no clamp needed:
            // fast-window parallelogram is strictly interior, j in [1,508])
            float4 sreg[8];
            if (nxtF) {
                const int gb = g0 + 32;
                #pragma unroll
                for (int u = 0; u < 8; ++u)
                    sreg[u] = *reinterpret_cast<const float4*>(
                        Dbat + (lbase + u * (8 * 511) + gb));
            }

            const float* rb = stageW + (q & 1) * SBUF + lane;
            float4 expv[8];                 // packed boundary values for ring export

            auto body = [&](auto FASTC) {
                constexpr bool FAST = decltype(FASTC)::value;
                #pragma unroll
                for (int s = 0; s < 32; ++s) {
                    const int g = g0 + s;
                    const float mn = fminf(nb2, fminf(nb1, own));
                    const float e  = __builtin_amdgcn_exp2f(mn - nb2)
                                   + __builtin_amdgcn_exp2f(mn - nb1)
                                   + __builtin_amdgcn_exp2f(mn - own);
                    const float sm = mn - __builtin_amdgcn_logf(e);   // log2
                    float v = (FAST ? rb[s * STRIDE] : Dslow[s]) + sm;
                    if (!FAST) {
                        const bool jok = (unsigned)(g - r) < (unsigned)Mc;
                        v = (jok && iok) ? v : BIGc;
                        res = (g == gcap) ? v : res;   // capture (always slow window)
                    }
                    f4set(expv[s >> 2], s, v);
                    const float sh = dpp_shr1_f(v, BIGc);
                    nb2 = nb1;
                    nb1 = l0 ? f4c(rv[s >> 2], s) : sh;
                    own = v;
                }
            };
            if (fastC) body(TrueC{}); else body(FalseC{});

            // LDS-write the staged tile LATE (global latency hidden under body)
            if (nxtF) {
                float* wb = stageW + ((q + 1) & 1) * SBUF + wbw;
                #pragma unroll
                for (int u = 0; u < 8; ++u) {
                    wb[0 * STRIDE + u * 8] = sreg[u].x;
                    wb[1 * STRIDE + u * 8] = sreg[u].y;
                    wb[2 * STRIDE + u * 8] = sreg[u].z;
                    wb[3 * STRIDE + u * 8] = sreg[u].w;
                }
            }
            // ring export: 8x b128 from packed regs (lane 63 only)
            if (W < 7 && lane == 63) {
                float* re = lds + RING_OFF + (W + 1) * 64 + (g0 & 63);
                #pragma unroll
                for (int u = 0; u < 8; ++u)
                    reinterpret_cast<float4*>(re)[u] = expv[u];
            }
            // prefetch Dslow for a boundary next-window
            if ((q + 1) <= ql && !nxtF) prefSlow(q + 1);
        }
        asm volatile("s_waitcnt lgkmcnt(0)" ::: "memory");  // ring/stage writes visible
        __builtin_amdgcn_s_barrier();                       // no vmcnt drain
        asm volatile("" ::: "memory");
    }

    if (i == L) out[b] = res * LN2;
}

// ---------------- Fallback (no workspace): fused on-the-fly D --------------------
__global__ __launch_bounds__(512)
void softdtw_fused(const float* __restrict__ X, const float* __restrict__ Y,
                   const int* __restrict__ lengths, float* __restrict__ out)
{
    const int b = blockIdx.x;
    const int t = threadIdx.x;
    const int i = t + 1;
    const int L = lengths[b];

    __shared__ float diag[3][Nc + 1];
    for (int c = t; c <= Nc; c += 512) {
        diag[0][c] = (c == 0) ? 0.f : BIGc;
        diag[1][c] = BIGc;
    }
    float xr[DIMc];
    const float* Xrow = X + ((size_t)b * Nc + t) * DIMc;
    #pragma unroll
    for (int d = 0; d < DIMc; d += 4) {
        float4 v = *reinterpret_cast<const float4*>(Xrow + d);
        xr[d] = v.x; xr[d+1] = v.y; xr[d+2] = v.z; xr[d+3] = v.w;
    }
    const float* Yb = Y + (size_t)b * Mc * DIMc;
    __syncthreads();

    float result = BIGc;
    int cur = 2, p1 = 1, p2 = 0;
    for (int k = 2; k <= Nc + Mc; ++k) {
        const int j = k - i;
        const bool valid = (j >= 1) && (j <= Mc) && (i <= L);
        float Dval = 0.f;
        if (valid) {
            const float* Yrow = Yb + (size_t)(j - 1) * DIMc;
            float s = 0.f;
            #pragma unroll
            for (int d = 0; d < DIMc; d += 4) {
                float4 v = *reinterpret_cast<const float4*>(Yrow + d);
                float d0 = xr[d] - v.x, d1 = xr[d+1] - v.y;
                float d2 = xr[d+2] - v.z, d3 = xr[d+3] - v.w;
                s = fmaf(d0,d0,s); s = fmaf(d1,d1,s); s = fmaf(d2,d2,s); s = fmaf(d3,d3,s);
            }
            Dval = s;
        }
        const float a2 = diag[p2][i-1], a1 = diag[p1][i-1], a0 = diag[p1][i];
        const float mn = fminf(a2, fminf(a1, a0));
        const float sm = mn - __logf(__expf(mn-a2) + __expf(mn-a1) + __expf(mn-a0));
        const float val = valid ? (Dval + sm) : BIGc;
        diag[cur][i] = val;
        if (t == 0) diag[cur][0] = BIGc;
        if (k == L + Mc && i == L) result = val;
        __syncthreads();
        const int tmp = p2; p2 = p1; p1 = cur; cur = tmp;
    }
    if (i == L) out[b] = result;
}

extern "C" void kernel_launch(void* const* d_in, const int* in_sizes, int n_in,
                              void* d_out, int out_size, void* d_ws, size_t ws_size,
                              hipStream_t stream) {
    const float* X = (const float*)d_in[0];
    const float* Y = (const float*)d_in[1];
    const int* lengths = (const int*)d_in[2];
    float* out = (float*)d_out;

    const size_t need = (size_t)Bc * CELLS * sizeof(float);   // 64 MiB
    if (ws_size >= need) {
        float* Dc = (float*)d_ws;
        compute_D<<<dim3(Bc, Nc / 64), 256, 0, stream>>>(X, Y, Dc);
        softdtw_sys8<<<Bc, 512, LDS_WORDS * 4, stream>>>(Dc, lengths, out);
    } else {
        softdtw_fused<<<Bc, 512, 0, stream>>>(X, Y, lengths, out);
    }
}